// Round 1
// baseline (810.202 us; speedup 1.0000x reference)
//
#include <hip/hip_runtime.h>
#include <stdint.h>

#define BB 64
#define NN 4096
#define DD 256
#define SS 8
#define NITER 3
#define EPS_LN 1e-5f
#define EPS_ATTN 1e-8f

typedef __attribute__((ext_vector_type(4))) float fvec4;
typedef __attribute__((ext_vector_type(8))) __bf16 bf16x8;
typedef __attribute__((ext_vector_type(8))) unsigned short usvec8;
typedef __attribute__((ext_vector_type(4))) unsigned short usvec4;

__device__ __forceinline__ float bf2f(unsigned short u) {
  return __uint_as_float(((unsigned)u) << 16);
}
__device__ __forceinline__ unsigned short f2bf(float f) {
  unsigned u = __float_as_uint(f);
  u += 0x7FFFu + ((u >> 16) & 1u);
  return (unsigned short)(u >> 16);
}
__device__ __forceinline__ void async_copy16(void* ldsp, const void* gp) {
  __builtin_amdgcn_global_load_lds(
      (const __attribute__((address_space(1))) unsigned int*)gp,
      (__attribute__((address_space(3))) unsigned int*)ldsp, 16, 0, 0);
}

// ---------------- init: slots broadcast ----------------
__global__ void k_sinit(const float* __restrict__ slots_init, float* __restrict__ slots) {
  int b = blockIdx.x, t = threadIdx.x;
  const fvec4* src = (const fvec4*)slots_init;
  fvec4* dst = (fvec4*)(slots + (size_t)b * SS * DD);
  for (int j = t; j < SS * DD / 4; j += 256) dst[j] = src[j];
}

// ---------------- init: wkv_t[c][k] = bf16( c<256 ? Wk[k][c] : Wv[k][c-256] ) ----------------
__global__ void k_wprep(const float* __restrict__ Wk, const float* __restrict__ Wv,
                        unsigned short* __restrict__ wkv) {
  int c = blockIdx.x, t = threadIdx.x;
  const float* W = (c < DD) ? Wk : Wv;
  int cc = c & (DD - 1);
  int k = t * 4;
  usvec4 o;
  o[0] = f2bf(W[(k + 0) * DD + cc]);
  o[1] = f2bf(W[(k + 1) * DD + cc]);
  o[2] = f2bf(W[(k + 2) * DD + cc]);
  o[3] = f2bf(W[(k + 3) * DD + cc]);
  *(usvec4*)&wkv[c * DD + k] = o;
}

// ---------------- A1: x = LN(inputs)*g+b -> bf16 ----------------
__launch_bounds__(256)
__global__ void k_ln_in(const float* __restrict__ in, const float* __restrict__ g,
                        const float* __restrict__ bt, unsigned short* __restrict__ xbf) {
  int t = threadIdx.x;
  long row = (long)blockIdx.x * 32 + (t >> 3);
  int sub = t & 7;
  const float* rp = in + row * DD + sub * 32;
  fvec4 v[8];
  float s = 0.f, s2 = 0.f;
#pragma unroll
  for (int j = 0; j < 8; j++) {
    v[j] = *(const fvec4*)(rp + j * 4);
    s += v[j].x + v[j].y + v[j].z + v[j].w;
    s2 += v[j].x * v[j].x + v[j].y * v[j].y + v[j].z * v[j].z + v[j].w * v[j].w;
  }
  s += __shfl_xor(s, 1); s2 += __shfl_xor(s2, 1);
  s += __shfl_xor(s, 2); s2 += __shfl_xor(s2, 2);
  s += __shfl_xor(s, 4); s2 += __shfl_xor(s2, 4);
  float mu = s / DD;
  float rs = rsqrtf(s2 / DD - mu * mu + EPS_LN);
  unsigned short o[32];
#pragma unroll
  for (int j = 0; j < 8; j++) {
    fvec4 gg = *(const fvec4*)(g + sub * 32 + j * 4);
    fvec4 bb = *(const fvec4*)(bt + sub * 32 + j * 4);
    o[j * 4 + 0] = f2bf((v[j].x - mu) * rs * gg.x + bb.x);
    o[j * 4 + 1] = f2bf((v[j].y - mu) * rs * gg.y + bb.y);
    o[j * 4 + 2] = f2bf((v[j].z - mu) * rs * gg.z + bb.z);
    o[j * 4 + 3] = f2bf((v[j].w - mu) * rs * gg.w + bb.w);
  }
  usvec8* op = (usvec8*)(xbf + row * DD + sub * 32);
#pragma unroll
  for (int j2 = 0; j2 < 4; j2++) {
    usvec8 u;
#pragma unroll
    for (int e = 0; e < 8; e++) u[e] = o[j2 * 8 + e];
    op[j2] = u;
  }
}

// ---------------- A2: [262144 x 512] = x_bf16 @ Wkv_t^T  (+bias) -> k,v bf16 ----------------
__launch_bounds__(256, 2)
__global__ void k_gemm_kv(const unsigned short* __restrict__ xbf,
                          const unsigned short* __restrict__ wkv,
                          const float* __restrict__ bk, const float* __restrict__ bv,
                          unsigned short* __restrict__ kout, unsigned short* __restrict__ vout) {
  __shared__ __attribute__((aligned(16))) unsigned short lA[128 * 64];
  __shared__ __attribute__((aligned(16))) unsigned short lB[128 * 64];
  int t = threadIdx.x;
  int w = t >> 6, lane = t & 63;
  int wr = w >> 1, wc = w & 1;
  long bm = blockIdx.x;
  int bn = blockIdx.y;
  fvec4 acc[4][4] = {};
  const unsigned short* abase = xbf + (bm * 128) * DD;
  const unsigned short* bbase = wkv + ((long)bn * 128) * DD;
  int lrow = lane >> 3, lcol = (lane & 7) * 8;
  for (int k0 = 0; k0 < DD; k0 += 64) {
    __syncthreads();
#pragma unroll
    for (int j = 0; j < 4; j++) {
      int chunk = w * 4 + j;
      async_copy16(&lA[chunk * 512], abase + (long)(chunk * 8 + lrow) * DD + k0 + lcol);
      async_copy16(&lB[chunk * 512], bbase + (long)(chunk * 8 + lrow) * DD + k0 + lcol);
    }
    __syncthreads();
#pragma unroll
    for (int ks = 0; ks < 2; ks++) {
      bf16x8 af[4], bfr[4];
#pragma unroll
      for (int m = 0; m < 4; m++)
        af[m] = *(const bf16x8*)&lA[(wr * 64 + m * 16 + (lane & 15)) * 64 + ks * 32 + (lane >> 4) * 8];
#pragma unroll
      for (int n = 0; n < 4; n++)
        bfr[n] = *(const bf16x8*)&lB[(wc * 64 + n * 16 + (lane & 15)) * 64 + ks * 32 + (lane >> 4) * 8];
#pragma unroll
      for (int m = 0; m < 4; m++)
#pragma unroll
        for (int n = 0; n < 4; n++)
          acc[m][n] = __builtin_amdgcn_mfma_f32_16x16x32_bf16(af[m], bfr[n], acc[m][n], 0, 0, 0);
    }
  }
  int cl = lane & 15, rg = lane >> 4;
#pragma unroll
  for (int n = 0; n < 4; n++) {
    int c = bn * 128 + wc * 64 + n * 16 + cl;
    bool isk = (c < DD);
    int c2 = c & (DD - 1);
    float bias = isk ? bk[c2] : bv[c2];
    unsigned short* op = isk ? kout : vout;
#pragma unroll
    for (int m = 0; m < 4; m++) {
      long r = bm * 128 + wr * 64 + m * 16 + rg * 4;
#pragma unroll
      for (int e = 0; e < 4; e++) {
        op[(r + e) * DD + c2] = f2bf(acc[m][n][e] + bias);
      }
    }
  }
}

// ---------------- I1: s = LN(slots); q = (s@Wq + bq) * D^-0.5 ; zero colsum/updates ----------------
__launch_bounds__(256)
__global__ void k_slotq(const float* __restrict__ slots, const float* __restrict__ g_s,
                        const float* __restrict__ b_s, const float* __restrict__ Wq,
                        const float* __restrict__ bq, float* __restrict__ qout,
                        float* __restrict__ colsum, float* __restrict__ updates) {
  __shared__ float sl[SS][DD];
  int b = blockIdx.x, t = threadIdx.x;
  for (int j = t; j < SS * DD; j += 256) updates[b * SS * DD + j] = 0.f;
  if (t < SS) colsum[b * SS + t] = 0.f;
  int row = t >> 5, seg = t & 31;
  float v[8];
  const float* sp = slots + (size_t)(b * SS + row) * DD + seg * 8;
  float s = 0.f, s2 = 0.f;
#pragma unroll
  for (int e = 0; e < 8; e++) { v[e] = sp[e]; s += v[e]; s2 += v[e] * v[e]; }
#pragma unroll
  for (int m = 16; m >= 1; m >>= 1) { s += __shfl_xor(s, m); s2 += __shfl_xor(s2, m); }
  float mu = s / DD;
  float rs = rsqrtf(s2 / DD - mu * mu + EPS_LN);
#pragma unroll
  for (int e = 0; e < 8; e++) {
    int d = seg * 8 + e;
    sl[row][d] = (v[e] - mu) * rs * g_s[d] + b_s[d];
  }
  __syncthreads();
  float acc[SS];
  float qb = bq[t];
#pragma unroll
  for (int i = 0; i < SS; i++) acc[i] = qb;
  for (int k = 0; k < DD; k += 4) {
    float w0 = Wq[(k + 0) * DD + t];
    float w1 = Wq[(k + 1) * DD + t];
    float w2 = Wq[(k + 2) * DD + t];
    float w3 = Wq[(k + 3) * DD + t];
#pragma unroll
    for (int i = 0; i < SS; i++) {
      fvec4 hv = *(const fvec4*)&sl[i][k];
      acc[i] += hv.x * w0 + hv.y * w1 + hv.z * w2 + hv.w * w3;
    }
  }
#pragma unroll
  for (int i = 0; i < SS; i++) qout[(size_t)(b * SS + i) * DD + t] = acc[i] * 0.0625f;
}

// ---------------- I2: dots + column softmax (+mask) -> attn_un; colsum atomics ----------------
__launch_bounds__(256)
__global__ void k_dots(const unsigned short* __restrict__ kbf, const float* __restrict__ qs,
                       const int* __restrict__ mask, float* __restrict__ attn,
                       float* __restrict__ colsum) {
  __shared__ float ql[SS][DD];
  int b = blockIdx.y, t = threadIdx.x;
  int c0 = blockIdx.x * 512;
  {
    const fvec4* src = (const fvec4*)(qs + (size_t)b * SS * DD);
    fvec4* dst = (fvec4*)ql;
    for (int j = t; j < SS * DD / 4; j += 256) dst[j] = src[j];
  }
  __syncthreads();
  float dots[2][SS] = {};
  const unsigned short* kb = kbf + ((long)b * NN + c0 + t) * DD;
  for (int d0 = 0; d0 < DD; d0 += 8) {
    float kf[2][8];
#pragma unroll
    for (int j = 0; j < 2; j++) {
      usvec8 kv = *(const usvec8*)(kb + (long)j * 256 * DD + d0);
#pragma unroll
      for (int e = 0; e < 8; e++) kf[j][e] = bf2f(kv[e]);
    }
#pragma unroll
    for (int i = 0; i < SS; i++) {
      fvec4 qa = *(const fvec4*)&ql[i][d0];
      fvec4 qb = *(const fvec4*)&ql[i][d0 + 4];
#pragma unroll
      for (int j = 0; j < 2; j++) {
        dots[j][i] += kf[j][0] * qa.x + kf[j][1] * qa.y + kf[j][2] * qa.z + kf[j][3] * qa.w +
                      kf[j][4] * qb.x + kf[j][5] * qb.y + kf[j][6] * qb.z + kf[j][7] * qb.w;
      }
    }
  }
  float cs[SS];
#pragma unroll
  for (int i = 0; i < SS; i++) cs[i] = 0.f;
#pragma unroll
  for (int j = 0; j < 2; j++) {
    int n = c0 + j * 256 + t;
    float a[SS];
    if (mask[(size_t)b * NN + n]) {
#pragma unroll
      for (int i = 0; i < SS; i++) a[i] = 0.125f;
    } else {
      float mx = dots[j][0];
#pragma unroll
      for (int i = 1; i < SS; i++) mx = fmaxf(mx, dots[j][i]);
      float sum = 0.f;
#pragma unroll
      for (int i = 0; i < SS; i++) { a[i] = __expf(dots[j][i] - mx); sum += a[i]; }
      float inv = 1.f / sum;
#pragma unroll
      for (int i = 0; i < SS; i++) a[i] *= inv;
    }
#pragma unroll
    for (int i = 0; i < SS; i++) {
      attn[((long)(b * SS + i)) * NN + n] = a[i];
      cs[i] += a[i];
    }
  }
#pragma unroll
  for (int m = 32; m >= 1; m >>= 1)
#pragma unroll
    for (int i = 0; i < SS; i++) cs[i] += __shfl_xor(cs[i], m);
  if ((t & 63) == 0) {
#pragma unroll
    for (int i = 0; i < SS; i++) atomicAdd(&colsum[b * SS + i], cs[i]);
  }
}

// ---------------- I3: updates_un[b,i,d] += sum_n attn_un[b,i,n] * v[b,n,d] ----------------
__launch_bounds__(256)
__global__ void k_upd(const unsigned short* __restrict__ vbf, const float* __restrict__ attn,
                      float* __restrict__ updates) {
  __shared__ float red[4][SS][DD];
  int b = blockIdx.y, t = threadIdx.x;
  int c0 = blockIdx.x * 512;
  int d0 = (t & 31) * 8, ns = t >> 5;
  float acc[SS][8] = {};
  const unsigned short* vb = vbf + ((long)(b * NN + c0 + ns)) * DD + d0;
  const float* ab = attn + (long)b * SS * NN + c0 + ns;
  for (int s8 = 0; s8 < 64; s8++) {
    int n = s8 * 8;
    usvec8 vv = *(const usvec8*)(vb + (long)n * DD);
    float vf[8];
#pragma unroll
    for (int e = 0; e < 8; e++) vf[e] = bf2f(vv[e]);
#pragma unroll
    for (int i = 0; i < SS; i++) {
      float aw = ab[(long)i * NN + n];
#pragma unroll
      for (int e = 0; e < 8; e++) acc[i][e] += aw * vf[e];
    }
  }
#pragma unroll
  for (int i = 0; i < SS; i++)
#pragma unroll
    for (int e = 0; e < 8; e++) acc[i][e] += __shfl_xor(acc[i][e], 32);
  int w = t >> 6, l = t & 63;
  if (l < 32) {
#pragma unroll
    for (int i = 0; i < SS; i++) {
      fvec4 a0 = {acc[i][0], acc[i][1], acc[i][2], acc[i][3]};
      fvec4 a1 = {acc[i][4], acc[i][5], acc[i][6], acc[i][7]};
      *(fvec4*)&red[w][i][l * 8] = a0;
      *(fvec4*)&red[w][i][l * 8 + 4] = a1;
    }
  }
  __syncthreads();
  int i2 = t >> 5, dsg = (t & 31) * 8;
#pragma unroll
  for (int e = 0; e < 8; e++) {
    float sum = red[0][i2][dsg + e] + red[1][i2][dsg + e] + red[2][i2][dsg + e] + red[3][i2][dsg + e];
    atomicAdd(&updates[(size_t)(b * SS + i2) * DD + dsg + e], sum);
  }
}

// ---------------- I4: slots += updates/(colsum+eps); MLP residual; optional final LN -> out ----------------
__launch_bounds__(256)
__global__ void k_mlp(float* __restrict__ slots, const float* __restrict__ colsum,
                      const float* __restrict__ updates, const float* __restrict__ g_m,
                      const float* __restrict__ b_m, const float* __restrict__ W1,
                      const float* __restrict__ b1, const float* __restrict__ W2,
                      const float* __restrict__ b2, const float* __restrict__ g_o,
                      const float* __restrict__ b_o, float* __restrict__ out, int is_last) {
  __shared__ float sn[SS][DD];
  __shared__ float h[SS][DD];
  __shared__ float h2[SS][DD];
  int b = blockIdx.x, t = threadIdx.x;
#pragma unroll
  for (int i = 0; i < SS; i++) {
    float inv = 1.0f / (colsum[b * SS + i] + EPS_ATTN);
    sn[i][t] = slots[(size_t)(b * SS + i) * DD + t] + updates[(size_t)(b * SS + i) * DD + t] * inv;
  }
  __syncthreads();
  int row = t >> 5, seg = t & 31;
  {
    float s = 0.f, s2 = 0.f;
#pragma unroll
    for (int e = 0; e < 8; e++) {
      float vv = sn[row][seg * 8 + e];
      s += vv; s2 += vv * vv;
    }
#pragma unroll
    for (int m = 16; m >= 1; m >>= 1) { s += __shfl_xor(s, m); s2 += __shfl_xor(s2, m); }
    float mu = s / DD;
    float rs = rsqrtf(s2 / DD - mu * mu + EPS_LN);
#pragma unroll
    for (int e = 0; e < 8; e++) {
      int d = seg * 8 + e;
      h[row][d] = (sn[row][d] - mu) * rs * g_m[d] + b_m[d];
    }
  }
  __syncthreads();
  {
    float acc[SS];
    float bb = b1[t];
#pragma unroll
    for (int i = 0; i < SS; i++) acc[i] = bb;
    for (int k = 0; k < DD; k += 4) {
      float w0 = W1[(k + 0) * DD + t];
      float w1 = W1[(k + 1) * DD + t];
      float w2 = W1[(k + 2) * DD + t];
      float w3 = W1[(k + 3) * DD + t];
#pragma unroll
      for (int i = 0; i < SS; i++) {
        fvec4 hv = *(const fvec4*)&h[i][k];
        acc[i] += hv.x * w0 + hv.y * w1 + hv.z * w2 + hv.w * w3;
      }
    }
#pragma unroll
    for (int i = 0; i < SS; i++) h2[i][t] = fmaxf(acc[i], 0.f);
  }
  __syncthreads();
  {
    float acc[SS];
    float bb = b2[t];
#pragma unroll
    for (int i = 0; i < SS; i++) acc[i] = bb;
    for (int k = 0; k < DD; k += 4) {
      float w0 = W2[(k + 0) * DD + t];
      float w1 = W2[(k + 1) * DD + t];
      float w2 = W2[(k + 2) * DD + t];
      float w3 = W2[(k + 3) * DD + t];
#pragma unroll
      for (int i = 0; i < SS; i++) {
        fvec4 hv = *(const fvec4*)&h2[i][k];
        acc[i] += hv.x * w0 + hv.y * w1 + hv.z * w2 + hv.w * w3;
      }
    }
#pragma unroll
    for (int i = 0; i < SS; i++) {
      float sf = sn[i][t] + acc[i];
      slots[(size_t)(b * SS + i) * DD + t] = sf;
      h[i][t] = sf;
    }
  }
  if (is_last) {
    __syncthreads();
    float s = 0.f, s2 = 0.f;
#pragma unroll
    for (int e = 0; e < 8; e++) {
      float vv = h[row][seg * 8 + e];
      s += vv; s2 += vv * vv;
    }
#pragma unroll
    for (int m = 16; m >= 1; m >>= 1) { s += __shfl_xor(s, m); s2 += __shfl_xor(s2, m); }
    float mu = s / DD;
    float rs = rsqrtf(s2 / DD - mu * mu + EPS_LN);
#pragma unroll
    for (int e = 0; e < 8; e++) {
      int d = seg * 8 + e;
      out[(size_t)(b * SS + row) * DD + d] = (h[row][d] - mu) * rs * g_o[d] + b_o[d];
    }
  }
}

extern "C" void kernel_launch(void* const* d_in, const int* in_sizes, int n_in,
                              void* d_out, int out_size, void* d_ws, size_t ws_size,
                              hipStream_t stream) {
  (void)in_sizes; (void)n_in; (void)out_size; (void)ws_size;
  const float* inputs = (const float*)d_in[0];
  const int* mask = (const int*)d_in[1];
  const float* slots_init = (const float*)d_in[2];
  const float* g_in = (const float*)d_in[3];
  const float* b_in = (const float*)d_in[4];
  const float* g_s = (const float*)d_in[5];
  const float* b_s = (const float*)d_in[6];
  const float* g_m = (const float*)d_in[7];
  const float* b_m = (const float*)d_in[8];
  const float* g_o = (const float*)d_in[9];
  const float* b_o = (const float*)d_in[10];
  const float* Wq = (const float*)d_in[11];
  const float* bq = (const float*)d_in[12];
  const float* Wk = (const float*)d_in[13];
  const float* bk = (const float*)d_in[14];
  const float* Wv = (const float*)d_in[15];
  const float* bv = (const float*)d_in[16];
  const float* W1 = (const float*)d_in[17];
  const float* b1 = (const float*)d_in[18];
  const float* W2 = (const float*)d_in[19];
  const float* b2 = (const float*)d_in[20];
  float* out = (float*)d_out;

  char* ws = (char*)d_ws;
  size_t off = 0;
  auto alloc = [&](size_t bytes) -> void* {
    void* p = ws + off;
    off += (bytes + 255) & ~(size_t)255;
    return p;
  };
  unsigned short* xbf = (unsigned short*)alloc((size_t)BB * NN * DD * 2);
  unsigned short* kbf = (unsigned short*)alloc((size_t)BB * NN * DD * 2);
  unsigned short* vbf = (unsigned short*)alloc((size_t)BB * NN * DD * 2);
  unsigned short* wkv = (unsigned short*)alloc((size_t)2 * DD * DD * 2);
  float* attn = (float*)alloc((size_t)BB * SS * NN * 4);
  float* q = (float*)alloc((size_t)BB * SS * DD * 4);
  float* slots = (float*)alloc((size_t)BB * SS * DD * 4);
  float* upd = (float*)alloc((size_t)BB * SS * DD * 4);
  float* colsum = (float*)alloc((size_t)BB * SS * 4);

  k_sinit<<<dim3(BB), dim3(256), 0, stream>>>(slots_init, slots);
  k_wprep<<<dim3(2 * DD), dim3(64), 0, stream>>>(Wk, Wv, wkv);
  k_ln_in<<<dim3(BB * NN / 32), dim3(256), 0, stream>>>(inputs, g_in, b_in, xbf);
  k_gemm_kv<<<dim3(BB * NN / 128, 4), dim3(256), 0, stream>>>(xbf, wkv, bk, bv, kbf, vbf);

  for (int it = 0; it < NITER; ++it) {
    k_slotq<<<dim3(BB), dim3(256), 0, stream>>>(slots, g_s, b_s, Wq, bq, q, colsum, upd);
    k_dots<<<dim3(NN / 512, BB), dim3(256), 0, stream>>>(kbf, q, mask, attn, colsum);
    k_upd<<<dim3(NN / 512, BB), dim3(256), 0, stream>>>(vbf, attn, upd);
    k_mlp<<<dim3(BB), dim3(256), 0, stream>>>(slots, colsum, upd, g_m, b_m, W1, b1, W2, b2,
                                              g_o, b_o, out, it == NITER - 1 ? 1 : 0);
  }
}